// Round 2
// baseline (80.421 us; speedup 1.0000x reference)
//
#include <hip/hip_runtime.h>
#include <math.h>

constexpr int PAD = 0;
constexpr int Lc = 128;   // sequence length
constexpr int Dc = 128;   // embedding dim
constexpr float MIN_NORM = 1e-15f;
constexpr float CLAMP_ABS_EPS = 1e-10f;
constexpr float ATANH_EPS = 1e-7f;

__device__ __forceinline__ float red64(float v) {
    v += __shfl_xor(v, 32);
    v += __shfl_xor(v, 16);
    v += __shfl_xor(v, 8);
    v += __shfl_xor(v, 4);
    v += __shfl_xor(v, 2);
    v += __shfl_xor(v, 1);
    return v;
}

// ---- pass 1: lam[v] = 2 / clip(1 - ||emb[v]||^2, 1e-15)  (one wave per row) ----
__global__ __launch_bounds__(256) void lam_kernel(
        const float* __restrict__ emb, float* __restrict__ lam, int V) {
    const int row  = blockIdx.x * 4 + (threadIdx.x >> 6);
    const int lane = threadIdx.x & 63;
    if (row >= V) return;
    const float2 z = *reinterpret_cast<const float2*>(emb + (size_t)row * Dc + lane * 2);
    float p = red64(z.x * z.x + z.y * z.y);
    if (lane == 0) lam[row] = 2.0f / fmaxf(1.0f - p, MIN_NORM);
}

// ---- pass 2: gather + midpoint + logmap0, one block per batch row ----
__global__ __launch_bounds__(256) void hyper_enc_kernel(
        const int* __restrict__ padded,
        const float* __restrict__ emb,
        const float* __restrict__ lam,
        float* __restrict__ out) {
    const int b    = blockIdx.x;
    const int tid  = threadIdx.x;
    const int wave = tid >> 6;
    const int lane = tid & 63;
    const int half = lane >> 5;   // which token of the pair
    const int l32  = lane & 31;   // dim-group within token

    __shared__ int   sidx[Lc];
    __shared__ float slam[Lc];    // lam (0 for pad) per token
    __shared__ float s_num[8][Dc];
    __shared__ int   s_cnt;
    __shared__ float s_den[2];
    __shared__ float s_red[4];

    // ---- stage indices + per-token lam; count + sum(lam) via waves 0,1 ----
    int   myidx = 0;
    float mylam = 0.f;
    if (tid < Lc) {
        myidx = padded[(size_t)b * Lc + tid];
        sidx[tid] = myidx;
        mylam = (myidx != PAD) ? lam[myidx] : 0.0f;
        slam[tid] = mylam;
    }
    if (tid == 0) s_cnt = 0;
    __syncthreads();
    if (tid < Lc) {  // waves 0,1 fully active -> wave-uniform ballot
        unsigned long long bal = __ballot(myidx != PAD);
        if (lane == 0) atomicAdd(&s_cnt, (int)__popcll(bal));
        float sl = red64(mylam);
        if (lane == 0) s_den[wave] = sl;   // sum over active lam
    }

    // ---- main gather: pure fma loop, 2 tokens per wave-iteration ----
    float4 snum = make_float4(0.f, 0.f, 0.f, 0.f);
    const int lbase = wave * 32 + half;
    __syncthreads();
    #pragma unroll
    for (int j = 0; j < 16; ++j) {
        const int   l   = lbase + 2 * j;
        const int   idx = sidx[l];
        const float wl  = slam[l];
        const float4 z = *reinterpret_cast<const float4*>(emb + (size_t)idx * Dc + l32 * 4);
        snum.x = fmaf(wl, z.x, snum.x);
        snum.y = fmaf(wl, z.y, snum.y);
        snum.z = fmaf(wl, z.z, snum.z);
        snum.w = fmaf(wl, z.w, snum.w);
    }
    const int g = wave * 2 + half;
    *reinterpret_cast<float4*>(&s_num[g][l32 * 4]) = snum;
    __syncthreads();

    const int cnt = s_cnt;
    if (cnt == 0) {  // all-pad row -> zeros (block-uniform)
        for (int i = tid; i < 4 * Dc; i += 256)
            out[(size_t)b * (4 * Dc) + i] = 0.f;
        return;
    }
    // Sum_active(lam - 1) = Sum(lam_masked) - cnt
    const float Sd = (s_den[0] + s_den[1]) - (float)cnt;

    // ---- combine 8 partial nominators ----
    float nom = 0.f;
    if (tid < Dc) {
        #pragma unroll
        for (int gg = 0; gg < 8; ++gg) nom += s_num[gg][tid];
    }

    // ---- two_mean (all four scales reduce to uniform weights 1/cnt) ----
    float tm = 0.f;
    if (tid < Dc) {
        const float rc    = 1.0f / (float)cnt;
        const float dn    = Sd * rc;
        const float denom = ((dn >= 0.f) ? 1.0f : -1.0f) * fmaxf(fabsf(dn), CLAMP_ABS_EPS);
        tm = (nom * rc) / denom;
    }

    // ---- ||two_mean|| over waves 0,1 ----
    float p2 = red64(tm * tm);
    if (lane == 0) s_red[wave] = p2;
    __syncthreads();
    const float n2sum = s_red[0] + s_red[1];
    const float n2 = fmaxf(sqrtf(n2sum), MIN_NORM);
    const float xc = fminf(n2, 1.0f - ATANH_EPS);
    // tanh(0.5 * artanh(x)) == x / (1 + sqrt(1 - x^2))
    const float t_half = xc / (1.0f + sqrtf(fmaxf(1.0f - xc * xc, 0.f)));
    const float mid = tm * (t_half / n2);

    // ---- ||mid|| ----
    __syncthreads();
    float q2 = red64(mid * mid);
    if (lane == 0) s_red[wave] = q2;
    __syncthreads();
    const float nmsum = s_red[0] + s_red[1];
    const float nm  = fmaxf(sqrtf(nmsum), MIN_NORM);
    const float xc2 = fminf(nm, 1.0f - ATANH_EPS);
    const float f   = 0.5f * logf((1.0f + xc2) / (1.0f - xc2));   // artanh

    // ---- logmap0 + replicate across the 4 scales ----
    if (tid < Dc) {
        const float o = mid * (f / nm);
        float* orow = out + (size_t)b * (4 * Dc);
        orow[0 * Dc + tid] = o;
        orow[1 * Dc + tid] = o;
        orow[2 * Dc + tid] = o;
        orow[3 * Dc + tid] = o;
    }
}

extern "C" void kernel_launch(void* const* d_in, const int* in_sizes, int n_in,
                              void* d_out, int out_size, void* d_ws, size_t ws_size,
                              hipStream_t stream) {
    const int*   padded = (const int*)d_in[0];
    const float* emb    = (const float*)d_in[1];
    float*       out    = (float*)d_out;
    float*       lam    = (float*)d_ws;          // V floats = 200 KB scratch
    const int Bn = in_sizes[0] / Lc;             // 8192
    const int V  = in_sizes[1] / Dc;             // 50000
    lam_kernel<<<(V + 3) / 4, 256, 0, stream>>>(emb, lam, V);
    hyper_enc_kernel<<<Bn, 256, 0, stream>>>(padded, emb, lam, out);
}

// Round 4
// 48.703 us; speedup vs baseline: 1.6512x; 1.6512x over previous
//
#include <hip/hip_runtime.h>
#include <hip/hip_fp16.h>
#include <math.h>

constexpr int PAD = 0;
constexpr int Lc = 128;   // sequence length
constexpr int Dc = 128;   // embedding dim
constexpr float MIN_NORM = 1e-15f;
constexpr float CLAMP_ABS_EPS = 1e-10f;
constexpr float ATANH_EPS = 1e-7f;

__device__ __forceinline__ float red64(float v) {
    v += __shfl_xor(v, 32);
    v += __shfl_xor(v, 16);
    v += __shfl_xor(v, 8);
    v += __shfl_xor(v, 4);
    v += __shfl_xor(v, 2);
    v += __shfl_xor(v, 1);
    return v;
}

// ---- pass 1: lam[v] = 2/clip(1-||emb[v]||^2) AND fp16 copy of the table ----
__global__ __launch_bounds__(256) void prep_kernel(
        const float* __restrict__ emb,
        __half* __restrict__ emb16,
        float* __restrict__ lam, int V) {
    const int row  = blockIdx.x * 4 + (threadIdx.x >> 6);
    const int lane = threadIdx.x & 63;
    if (row >= V) return;
    const float2 z = *reinterpret_cast<const float2*>(emb + (size_t)row * Dc + lane * 2);
    const float p = red64(z.x * z.x + z.y * z.y);
    if (lane == 0) lam[row] = 2.0f / fmaxf(1.0f - p, MIN_NORM);
    *reinterpret_cast<__half2*>(emb16 + (size_t)row * Dc + lane * 2) =
        __floats2half2_rn(z.x, z.y);
}

// ---- pass 2: fp16 gather + midpoint + logmap0, one block per batch row ----
__global__ __launch_bounds__(256) void hyper_enc_kernel(
        const int* __restrict__ padded,
        const __half* __restrict__ emb16,
        const float* __restrict__ lam,
        float* __restrict__ out) {
    const int b    = blockIdx.x;
    const int tid  = threadIdx.x;
    const int wave = tid >> 6;
    const int lane = tid & 63;
    const int half = lane >> 5;   // which token of the pair
    const int l32  = lane & 31;   // dim-group within token

    __shared__ int   sidx[Lc];
    __shared__ float slam[Lc];
    __shared__ float s_num[8][Dc];
    __shared__ int   s_cnt;
    __shared__ float s_den[2];
    __shared__ float s_red[4];

    // ---- stage indices + per-token lam; count + sum(lam) ----
    int   myidx = 0;
    float mylam = 0.f;
    if (tid < Lc) {
        myidx = padded[(size_t)b * Lc + tid];
        sidx[tid] = myidx;
        mylam = (myidx != PAD) ? lam[myidx] : 0.0f;
        slam[tid] = mylam;
    }
    if (tid == 0) s_cnt = 0;
    __syncthreads();
    if (tid < Lc) {  // waves 0,1 fully active
        unsigned long long bal = __ballot(myidx != PAD);
        if (lane == 0) atomicAdd(&s_cnt, (int)__popcll(bal));
        float sl = red64(mylam);
        if (lane == 0) s_den[wave] = sl;
    }

    // ---- main gather: fp16 rows, 2 tokens per wave-iteration, 8B/lane ----
    float4 snum = make_float4(0.f, 0.f, 0.f, 0.f);
    const int lbase = wave * 32 + half;
    __syncthreads();
    #pragma unroll
    for (int j = 0; j < 16; ++j) {
        const int   l   = lbase + 2 * j;
        const int   idx = sidx[l];
        const float wl  = slam[l];
        const float2 raw = *reinterpret_cast<const float2*>(
            emb16 + (size_t)idx * Dc + l32 * 4);
        const __half2 h0 = *reinterpret_cast<const __half2*>(&raw.x);
        const __half2 h1 = *reinterpret_cast<const __half2*>(&raw.y);
        const float2 f0 = __half22float2(h0);
        const float2 f1 = __half22float2(h1);
        snum.x = fmaf(wl, f0.x, snum.x);
        snum.y = fmaf(wl, f0.y, snum.y);
        snum.z = fmaf(wl, f1.x, snum.z);
        snum.w = fmaf(wl, f1.y, snum.w);
    }
    const int g = wave * 2 + half;
    *reinterpret_cast<float4*>(&s_num[g][l32 * 4]) = snum;
    __syncthreads();

    const int cnt = s_cnt;
    if (cnt == 0) {  // all-pad row -> zeros (block-uniform)
        for (int i = tid; i < 4 * Dc; i += 256)
            out[(size_t)b * (4 * Dc) + i] = 0.f;
        return;
    }
    const float Sd = (s_den[0] + s_den[1]) - (float)cnt;   // sum_active(lam-1)

    // ---- combine 8 partial nominators ----
    float nom = 0.f;
    if (tid < Dc) {
        #pragma unroll
        for (int gg = 0; gg < 8; ++gg) nom += s_num[gg][tid];
    }

    // ---- two_mean (all four scales -> uniform weights 1/cnt) ----
    float tm = 0.f;
    if (tid < Dc) {
        const float rc    = 1.0f / (float)cnt;
        const float dn    = Sd * rc;
        const float denom = ((dn >= 0.f) ? 1.0f : -1.0f) * fmaxf(fabsf(dn), CLAMP_ABS_EPS);
        tm = (nom * rc) / denom;
    }

    // ---- ||two_mean|| ----
    float p2 = red64(tm * tm);
    if (lane == 0) s_red[wave] = p2;
    __syncthreads();
    const float n2sum = s_red[0] + s_red[1];
    const float n2 = fmaxf(sqrtf(n2sum), MIN_NORM);
    const float xc = fminf(n2, 1.0f - ATANH_EPS);
    const float t_half = xc / (1.0f + sqrtf(fmaxf(1.0f - xc * xc, 0.f)));  // tanh(0.5*artanh)
    const float mid = tm * (t_half / n2);

    // ---- ||mid|| ----
    __syncthreads();
    float q2 = red64(mid * mid);
    if (lane == 0) s_red[wave] = q2;
    __syncthreads();
    const float nmsum = s_red[0] + s_red[1];
    const float nm  = fmaxf(sqrtf(nmsum), MIN_NORM);
    const float xc2 = fminf(nm, 1.0f - ATANH_EPS);
    const float f   = 0.5f * logf((1.0f + xc2) / (1.0f - xc2));   // artanh

    // ---- logmap0 + replicate across the 4 scales ----
    if (tid < Dc) {
        const float o = mid * (f / nm);
        float* orow = out + (size_t)b * (4 * Dc);
        orow[0 * Dc + tid] = o;
        orow[1 * Dc + tid] = o;
        orow[2 * Dc + tid] = o;
        orow[3 * Dc + tid] = o;
    }
}

// ---- fallback (ws too small): fp32 gather with inline norms (round-1 kernel) ----
__global__ __launch_bounds__(256) void hyper_enc_fp32_kernel(
        const int* __restrict__ padded,
        const float* __restrict__ emb,
        float* __restrict__ out) {
    const int b    = blockIdx.x;
    const int tid  = threadIdx.x;
    const int wave = tid >> 6;
    const int lane = tid & 63;
    const int half = lane >> 5;
    const int l32  = lane & 31;

    __shared__ int   sidx[Lc];
    __shared__ float s_num[8][Dc];
    __shared__ float s_den[8];
    __shared__ int   s_cnt;
    __shared__ float s_sd;
    __shared__ float s_red[4];

    int myidx = 0;
    if (tid < Lc) { myidx = padded[(size_t)b * Lc + tid]; sidx[tid] = myidx; }
    if (tid == 0) s_cnt = 0;
    __syncthreads();
    if (tid < Lc) {
        unsigned long long bal = __ballot(myidx != PAD);
        if (lane == 0) atomicAdd(&s_cnt, (int)__popcll(bal));
    }
    __syncthreads();

    float4 snum = make_float4(0.f, 0.f, 0.f, 0.f);
    float  sden = 0.f;
    const int lbase = wave * 32 + half;
    #pragma unroll 4
    for (int j = 0; j < 16; ++j) {
        const int idx = sidx[lbase + 2 * j];
        const float4 z = *reinterpret_cast<const float4*>(emb + (size_t)idx * Dc + l32 * 4);
        float p = z.x * z.x + z.y * z.y + z.z * z.z + z.w * z.w;
        p += __shfl_xor(p, 16); p += __shfl_xor(p, 8);
        p += __shfl_xor(p, 4);  p += __shfl_xor(p, 2); p += __shfl_xor(p, 1);
        const float lamv = 2.0f / fmaxf(1.0f - p, MIN_NORM);
        const bool  act = (idx != PAD);
        const float wl  = act ? lamv : 0.0f;
        sden += act ? (lamv - 1.0f) : 0.0f;
        snum.x = fmaf(wl, z.x, snum.x); snum.y = fmaf(wl, z.y, snum.y);
        snum.z = fmaf(wl, z.z, snum.z); snum.w = fmaf(wl, z.w, snum.w);
    }
    const int g = wave * 2 + half;
    *reinterpret_cast<float4*>(&s_num[g][l32 * 4]) = snum;
    if (l32 == 0) s_den[g] = sden;
    __syncthreads();

    float nom = 0.f;
    if (tid < Dc) {
        #pragma unroll
        for (int gg = 0; gg < 8; ++gg) nom += s_num[gg][tid];
    }
    if (tid == 0) {
        float t = 0.f;
        #pragma unroll
        for (int gg = 0; gg < 8; ++gg) t += s_den[gg];
        s_sd = t;
    }
    __syncthreads();

    const int cnt = s_cnt;
    if (cnt == 0) {
        for (int i = tid; i < 4 * Dc; i += 256) out[(size_t)b * (4 * Dc) + i] = 0.f;
        return;
    }
    const float Sd = s_sd;
    float tm = 0.f;
    if (tid < Dc) {
        const float rc = 1.0f / (float)cnt;
        const float dn = Sd * rc;
        const float denom = ((dn >= 0.f) ? 1.0f : -1.0f) * fmaxf(fabsf(dn), CLAMP_ABS_EPS);
        tm = (nom * rc) / denom;
    }
    float p2 = red64(tm * tm);
    if (lane == 0) s_red[wave] = p2;
    __syncthreads();
    const float n2 = fmaxf(sqrtf(s_red[0] + s_red[1]), MIN_NORM);
    const float xc = fminf(n2, 1.0f - ATANH_EPS);
    const float t_half = xc / (1.0f + sqrtf(fmaxf(1.0f - xc * xc, 0.f)));
    const float mid = tm * (t_half / n2);
    __syncthreads();
    float q2 = red64(mid * mid);
    if (lane == 0) s_red[wave] = q2;
    __syncthreads();
    const float nm  = fmaxf(sqrtf(s_red[0] + s_red[1]), MIN_NORM);
    const float xc2 = fminf(nm, 1.0f - ATANH_EPS);
    const float f   = 0.5f * logf((1.0f + xc2) / (1.0f - xc2));
    if (tid < Dc) {
        const float o = mid * (f / nm);
        float* orow = out + (size_t)b * (4 * Dc);
        orow[0 * Dc + tid] = o; orow[1 * Dc + tid] = o;
        orow[2 * Dc + tid] = o; orow[3 * Dc + tid] = o;
    }
}

extern "C" void kernel_launch(void* const* d_in, const int* in_sizes, int n_in,
                              void* d_out, int out_size, void* d_ws, size_t ws_size,
                              hipStream_t stream) {
    const int*   padded = (const int*)d_in[0];
    const float* emb    = (const float*)d_in[1];
    float*       out    = (float*)d_out;
    const int Bn = in_sizes[0] / Lc;             // 8192
    const int V  = in_sizes[1] / Dc;             // 50000

    const size_t emb16_bytes = (size_t)V * Dc * sizeof(__half);   // 12.8 MB
    const size_t lam_bytes   = (size_t)V * sizeof(float);         // 200 KB
    if (ws_size >= emb16_bytes + lam_bytes) {
        __half* emb16 = (__half*)d_ws;
        float*  lam   = (float*)((char*)d_ws + emb16_bytes);
        prep_kernel<<<(V + 3) / 4, 256, 0, stream>>>(emb, emb16, lam, V);
        hyper_enc_kernel<<<Bn, 256, 0, stream>>>(padded, emb16, lam, out);
    } else {
        hyper_enc_fp32_kernel<<<Bn, 256, 0, stream>>>(padded, emb, out);
    }
}